// Round 3
// baseline (184.610 us; speedup 1.0000x reference)
//
#include <hip/hip_runtime.h>

// Causal GQA attention: S=2048, H=32, KVH=8, D=128, fp32 in/out.
// R5: K->bf16 / V^T->bf16 pre-passes; global_load_lds staging into XOR-swizzled
// LDS; PV via 16x16x16 bf16 MFMA (B-frag == S^T C-layout, zero shuffles).
// R6: kf/vf register prefetch + s_setprio (neutral, kept minimal).
// R7: work-uniform blocks: each wave owns 16 rows of a heavy tile (sub0) and
// 16 of a light tile (sub1); per-block work uniform at 66 sub-iters.
// R8: T3/T4 pipeline. R5-R7 were stuck at ~81us = 32 iters x ~5300cyc: the
// per-iter fixed cost was the __syncthreads-implied vmcnt(0) drain of the
// just-issued DMA (2-phase structure, m233's 72%-overhead regime). Now:
// KVBLK=32, FOUR 16KB LDS buffers (same 64KB -> 2 blocks/CU), prefetch depth
// 2. Each iter: issue DMA(t+2); compute buf(t&3); s_waitcnt vmcnt(8) (drains
// ONLY t+1, t+2 stays in flight ACROSS the raw s_barrier). Never vmcnt(0) in
// steady state; DMA latency gets ~2 iterations of overlap.

#define SEQ   2048
#define NH    32
#define NKV   8
#define HD    128
#define QLD   4096      // NH*HD
#define KLD   1024      // NKV*HD
#define KVB   32        // keys per tile
#define VT_HEAD (HD * SEQ)   // elems per kv-head in V^T

typedef __attribute__((ext_vector_type(8))) __bf16 bf16x8;
typedef __attribute__((ext_vector_type(4))) __bf16 bf16x4;
typedef __attribute__((ext_vector_type(2))) __bf16 bf16x2;
typedef __attribute__((ext_vector_type(4))) float  f32x4;
typedef __attribute__((ext_vector_type(4))) short  s16x4;
typedef __attribute__((ext_vector_type(2))) unsigned int u32x2;

static __device__ __forceinline__ unsigned int pack2(float lo, float hi) {
  bf16x2 t; t[0] = (__bf16)lo; t[1] = (__bf16)hi;
  return __builtin_bit_cast(unsigned int, t);
}

// PV matmul: D = A(V^T frag, 2 VGPR) * B(P frag = S^T C-layout regs) + C
static __device__ __forceinline__ f32x4 mfma16(bf16x4 a, u32x2 b, f32x4 c) {
#if __has_builtin(__builtin_amdgcn_mfma_f32_16x16x16bf16_1k)
  return __builtin_amdgcn_mfma_f32_16x16x16bf16_1k(
      __builtin_bit_cast(s16x4, a), __builtin_bit_cast(s16x4, b), c, 0, 0, 0);
#else
  asm volatile("v_mfma_f32_16x16x16_bf16 %0, %1, %2, %0"
               : "+v"(c) : "v"(a), "v"(b));
  return c;
#endif
}

// ---- pre-pass 1: K fp32 -> bf16, same [2048][1024] layout ----
__global__ void convert_k(const float* __restrict__ k, __bf16* __restrict__ kb) {
  const int i = (blockIdx.x * 256 + threadIdx.x) * 4;
  float4 v = *(const float4*)(k + i);
  bf16x4 b;
  b[0] = (__bf16)v.x; b[1] = (__bf16)v.y; b[2] = (__bf16)v.z; b[3] = (__bf16)v.w;
  *(bf16x4*)(kb + i) = b;
}

// ---- pre-pass 2: V fp32 [key][kvh*128+dim] -> bf16 V^T [kvh][dim][key] ----
__global__ void transpose_v(const float* __restrict__ v, __bf16* __restrict__ vt) {
  __shared__ __bf16 TT[HD][72];   // [dim][key(64)+pad]
  const int kvh = blockIdx.y;
  const int kb  = blockIdx.x * 64;
  const int t   = threadIdx.x;
  {
    const int key = t >> 2, dq = t & 3;
    const float* vp = v + (size_t)(kb + key) * KLD + kvh * HD + dq * 32;
#pragma unroll
    for (int j = 0; j < 8; ++j) {
      float4 x = *(const float4*)(vp + j * 4);
      const int d = dq * 32 + j * 4;
      TT[d + 0][key] = (__bf16)x.x; TT[d + 1][key] = (__bf16)x.y;
      TT[d + 2][key] = (__bf16)x.z; TT[d + 3][key] = (__bf16)x.w;
    }
  }
  __syncthreads();
  {
    const int dim = t >> 1, kh = (t & 1) * 32;
    __bf16* op = vt + (size_t)kvh * VT_HEAD + (size_t)dim * SEQ + kb + kh;
#pragma unroll
    for (int j = 0; j < 8; ++j)
      *(bf16x4*)(op + j * 4) = *(const bf16x4*)&TT[dim][kh + j * 4];
  }
}

// ---- main kernel ----
__global__ __launch_bounds__(256, 2)
void fa_kernel(const float* __restrict__ q, const __bf16* __restrict__ kg,
               const __bf16* __restrict__ vt, float* __restrict__ out) {
  // Per buffer (16KB): K 8KB = 32 keys x 256B (16 chunks of 8 bf16, chunk
  // slot = c8 ^ (key&7)); V 8KB = 128 dims x 64B (4 chunks of 8 keys, slot =
  // kc2 ^ (dim&3)). 4 buffers each -> 64KB total, 2 blocks/CU.
  __shared__ __bf16 KB[4][4096];
  __shared__ __bf16 VB[4][4096];

  const int head = blockIdx.x;
  const int ip   = blockIdx.y;          // light 64-row tile = ip, heavy = 31-ip
  const int kvh  = head >> 2;
  const int tid  = threadIdx.x;
  const int wave = tid >> 6;
  const int lane = tid & 63;
  const int l15  = lane & 15;
  const int quad = lane >> 4;
  const int h3   = l15 & 7;

  // per-sub row bases: sub0 = heavy 16 rows, sub1 = light 16 rows
  const int rwS[2] = { (31 - ip) * 64 + wave * 16, ip * 64 + wave * 16 };

  constexpr float QS = 0.08838834764831845f * 1.4426950408889634f; // scale*log2e

  // Q fragments (B-operand of S^T = K*Q^T): B[k=quad*8+j][n=l15]
  bf16x8 qf[2][4];
#pragma unroll
  for (int sub = 0; sub < 2; ++sub) {
    const float* qp = q + (size_t)(rwS[sub] + l15) * QLD + head * HD + quad * 8;
#pragma unroll
    for (int c = 0; c < 4; ++c) {
      float4 a0 = *(const float4*)(qp + c * 32);
      float4 a1 = *(const float4*)(qp + c * 32 + 4);
      bf16x8 f;
      f[0] = (__bf16)(a0.x * QS); f[1] = (__bf16)(a0.y * QS);
      f[2] = (__bf16)(a0.z * QS); f[3] = (__bf16)(a0.w * QS);
      f[4] = (__bf16)(a1.x * QS); f[5] = (__bf16)(a1.y * QS);
      f[6] = (__bf16)(a1.z * QS); f[7] = (__bf16)(a1.w * QS);
      qf[sub][c] = f;
    }
  }

  // DMA lane->global offsets (elements). 2 K-instrs + 2 V-instrs per wave/tile.
  int kgo[2], vgo[2];
#pragma unroll
  for (int j = 0; j < 2; ++j) {
    const int key = (wave * 2 + j) * 4 + (lane >> 4);        // 0..31
    const int c8  = (lane & 15) ^ (key & 7);
    kgo[j] = key * KLD + kvh * HD + c8 * 8;
    const int dim = (wave * 2 + j) * 16 + (lane >> 2);       // 0..127
    const int kc2 = (lane & 3) ^ (dim & 3);
    vgo[j] = kvh * VT_HEAD + dim * SEQ + kc2 * 8;
  }

  auto dma_tile = [&](int tt) {
    const int kbase = tt * KVB;     // key offset
    const int buf   = tt & 3;
#pragma unroll
    for (int j = 0; j < 2; ++j)
      __builtin_amdgcn_global_load_lds(
          (const __attribute__((address_space(1))) unsigned int*)(kg + kbase * KLD + kgo[j]),
          (__attribute__((address_space(3))) unsigned int*)&KB[buf][(wave * 2 + j) * 512],
          16, 0, 0);
#pragma unroll
    for (int j = 0; j < 2; ++j)
      __builtin_amdgcn_global_load_lds(
          (const __attribute__((address_space(1))) unsigned int*)(vt + kbase + vgo[j]),
          (__attribute__((address_space(3))) unsigned int*)&VB[buf][(wave * 2 + j) * 512],
          16, 0, 0);
  };

  // fragment byte offsets inside a buffer (bank-uniform by construction)
  int kaddr[4], vaddr[2];
#pragma unroll
  for (int c = 0; c < 4; ++c)
    kaddr[c] = l15 * 256 + (((c * 4 + quad) ^ h3) * 16);
#pragma unroll
  for (int kt = 0; kt < 2; ++kt)
    vaddr[kt] = l15 * 64 + (((kt * 2 + (quad >> 1)) ^ (l15 & 3)) * 16) + (quad & 1) * 8;

  f32x4 acc[2][8];
  f32x4 lp[2];
#pragma unroll
  for (int sub = 0; sub < 2; ++sub) {
    lp[sub] = (f32x4){0.f, 0.f, 0.f, 0.f};
#pragma unroll
    for (int nt = 0; nt < 8; ++nt) acc[sub][nt] = (f32x4){0.f, 0.f, 0.f, 0.f};
  }

  const int ntiles = 64 - 2 * ip;   // 32-key tiles; heavy tile needs all of them

  // ---- prologue: Q loads fully consumed above; clean vmcnt counter ----
  __builtin_amdgcn_sched_barrier(0);
  dma_tile(0);
  dma_tile(1);
  asm volatile("s_waitcnt vmcnt(8)");        // tile 0 landed; tile 1 in flight
  __builtin_amdgcn_sched_barrier(0);
  __builtin_amdgcn_s_barrier();
  __builtin_amdgcn_sched_barrier(0);

  for (int t = 0; t < ntiles; ++t) {
    const int rb = t & 3;
    if (t + 2 < ntiles) dma_tile(t + 2);     // depth-2 prefetch

    const bool light_on = (t <= 2 * ip + 1); // block-uniform
    const char* Kb = (const char*)&KB[rb][0];
    const char* Vb = (const char*)&VB[rb][0];

    // ---- S^T = K*Q^T (C-layout: key = quad*4+e, row = l15), then exp2 ----
    u32x2 pk[2][2];
#pragma unroll
    for (int ng = 0; ng < 2; ++ng) {         // key group of 16
      bf16x8 kf[4];
#pragma unroll
      for (int c = 0; c < 4; ++c)
        kf[c] = *(const bf16x8*)(Kb + kaddr[c] + ng * 4096);
#pragma unroll
      for (int sub = 0; sub < 2; ++sub) {
        if (sub == 1 && !light_on) continue;
        f32x4 s = (f32x4){0.f, 0.f, 0.f, 0.f};
        __builtin_amdgcn_s_setprio(1);
#pragma unroll
        for (int c = 0; c < 4; ++c)
          s = __builtin_amdgcn_mfma_f32_16x16x32_bf16(kf[c], qf[sub][c], s, 0, 0, 0);
        __builtin_amdgcn_s_setprio(0);
        if (t * KVB + KVB - 1 > rwS[sub]) {  // causal mask (wave-uniform)
          const int key0  = t * KVB + ng * 16 + quad * 4;
          const int myrow = rwS[sub] + l15;
#pragma unroll
          for (int e = 0; e < 4; ++e)
            if (key0 + e > myrow) s[e] = -1e30f;
        }
        f32x4 p;
#pragma unroll
        for (int e = 0; e < 4; ++e) p[e] = __builtin_amdgcn_exp2f(s[e]);
        lp[sub] += p;
        u32x2 pkk;
        pkk.x = pack2(p[0], p[1]);
        pkk.y = pack2(p[2], p[3]);
        pk[sub][ng] = pkk;
      }
    }

    // ---- O^T += V^T * P  (16x16x16: B-frag = pk as-is, zero shuffles) ----
#pragma unroll
    for (int kt = 0; kt < 2; ++kt) {         // key group of 16
      bf16x4 vf[8];
#pragma unroll
      for (int nt = 0; nt < 8; ++nt)
        vf[nt] = *(const bf16x4*)(Vb + vaddr[kt] + nt * 1024);
      __builtin_amdgcn_s_setprio(1);
#pragma unroll
      for (int nt = 0; nt < 8; ++nt) {
        acc[0][nt] = mfma16(vf[nt], pk[0][kt], acc[0][nt]);
        if (light_on)
          acc[1][nt] = mfma16(vf[nt], pk[1][kt], acc[1][nt]);
      }
      __builtin_amdgcn_s_setprio(0);
    }

    // ---- counted drain + raw barrier: t+2's loads stay in flight ----
    if (t + 2 < ntiles) {
      asm volatile("s_waitcnt vmcnt(8)");    // t+1 landed; t+2 still flying
    } else if (t + 1 < ntiles) {
      asm volatile("s_waitcnt vmcnt(0)");    // tail: drain t+1
    }
    if (t + 1 < ntiles) {
      __builtin_amdgcn_sched_barrier(0);
      __builtin_amdgcn_s_barrier();
      __builtin_amdgcn_sched_barrier(0);
    }
  }

  // ---- epilogue: lane owns row l15 entirely -> scalar inv, float4 stores ----
#pragma unroll
  for (int sub = 0; sub < 2; ++sub) {
    float ls = lp[sub][0] + lp[sub][1] + lp[sub][2] + lp[sub][3];
    ls += __shfl_xor(ls, 16);
    ls += __shfl_xor(ls, 32);
    const float inv = 1.0f / ls;
    float* op = out + (size_t)(rwS[sub] + l15) * QLD + head * HD + quad * 4;
#pragma unroll
    for (int nt = 0; nt < 8; ++nt) {
      f32x4 r = acc[sub][nt];
      float4 w = {r[0] * inv, r[1] * inv, r[2] * inv, r[3] * inv};
      *(float4*)(op + nt * 16) = w;
    }
  }
}

extern "C" void kernel_launch(void* const* d_in, const int* in_sizes, int n_in,
                              void* d_out, int out_size, void* d_ws, size_t ws_size,
                              hipStream_t stream) {
  const float* q = (const float*)d_in[0];
  const float* k = (const float*)d_in[1];
  const float* v = (const float*)d_in[2];
  float* o = (float*)d_out;
  __bf16* kbf = (__bf16*)d_ws;                    // 4 MB: K as bf16
  __bf16* vtb = (__bf16*)d_ws + (size_t)SEQ * KLD; // 4 MB: V^T bf16
  convert_k<<<2048, 256, 0, stream>>>(k, kbf);
  transpose_v<<<dim3(32, 8), 256, 0, stream>>>(v, vtb);
  fa_kernel<<<dim3(32, 16), 256, 0, stream>>>(q, kbf, vtb, o);
}

// Round 4
// 178.034 us; speedup vs baseline: 1.0369x; 1.0369x over previous
//
#include <hip/hip_runtime.h>

// Causal GQA attention: S=2048, H=32, KVH=8, D=128, fp32 in/out.
// R5: K->bf16 / V^T->bf16 pre-passes; global_load_lds staging into XOR-swizzled
// LDS; PV via 16x16x16 bf16 MFMA (B-frag == S^T C-layout, zero shuffles).
// R7: work-uniform blocks: wave = 16 heavy rows (sub0) + 16 light rows (sub1).
// R8: KVB=32, 4-buffer ring, counted vmcnt across raw barriers. REGRESSED:
//   (a) V swizzle kc^(dim&3) gave 4-way bank conflicts (9.6M->22.5M);
//   (b) sched_barrier(0) fences everywhere pinned the scheduler;
//   (c) no cross-tile overlap, so doubling iters doubled the ~1800cyc/iter
//       fixed cost.
// R9: (1) V swizzle fixed to kc ^ ((dim>>1)&3) -> provably even 4-words/bank
// (b64 minimum) across the wave; (2) T15 phase-shift: PV lags QK by one tile,
// so PV(t-1)'s 16 independent MFMAs per group interleave with QK(t)'s
// dependent accumulate chain + softmax VALU/trans; 4-buffer ring keeps V(t-1)
// resident; (3) vmcnt(4) steady-state (t+2's batch stays in flight across the
// barrier), sched_barrier(0) only after the barrier; (4) pre-passes merged
// into one launch.

#define SEQ   2048
#define NH    32
#define NKV   8
#define HD    128
#define QLD   4096      // NH*HD
#define KLD   1024      // NKV*HD
#define KVB   32        // keys per tile
#define VT_HEAD (HD * SEQ)   // elems per kv-head in V^T

typedef __attribute__((ext_vector_type(8))) __bf16 bf16x8;
typedef __attribute__((ext_vector_type(4))) __bf16 bf16x4;
typedef __attribute__((ext_vector_type(2))) __bf16 bf16x2;
typedef __attribute__((ext_vector_type(4))) float  f32x4;
typedef __attribute__((ext_vector_type(4))) short  s16x4;
typedef __attribute__((ext_vector_type(2))) unsigned int u32x2;

static __device__ __forceinline__ unsigned int pack2(float lo, float hi) {
  bf16x2 t; t[0] = (__bf16)lo; t[1] = (__bf16)hi;
  return __builtin_bit_cast(unsigned int, t);
}

// PV matmul: D = A(V^T frag, 2 VGPR) * B(P frag = S^T C-layout regs) + C
static __device__ __forceinline__ f32x4 mfma16(bf16x4 a, u32x2 b, f32x4 c) {
#if __has_builtin(__builtin_amdgcn_mfma_f32_16x16x16bf16_1k)
  return __builtin_amdgcn_mfma_f32_16x16x16bf16_1k(
      __builtin_bit_cast(s16x4, a), __builtin_bit_cast(s16x4, b), c, 0, 0, 0);
#else
  asm volatile("v_mfma_f32_16x16x16_bf16 %0, %1, %2, %0"
               : "+v"(c) : "v"(a), "v"(b));
  return c;
#endif
}

// ---- merged pre-pass: K fp32->bf16 copy  +  V fp32 -> bf16 V^T ----
// blocks [0,2048): convert K. blocks [2048,2304): transpose V.
__global__ void prep_kv(const float* __restrict__ k, __bf16* __restrict__ kb,
                        const float* __restrict__ v, __bf16* __restrict__ vt) {
  __shared__ __bf16 TT[HD][72];   // [dim][key(64)+pad] (V part only)
  const int bx = blockIdx.x;
  const int t  = threadIdx.x;
  if (bx < 2048) {
    const int i = (bx * 256 + t) * 4;
    float4 x = *(const float4*)(k + i);
    bf16x4 b;
    b[0] = (__bf16)x.x; b[1] = (__bf16)x.y; b[2] = (__bf16)x.z; b[3] = (__bf16)x.w;
    *(bf16x4*)(kb + i) = b;
    return;
  }
  const int vb  = bx - 2048;
  const int kvh = vb >> 5;
  const int kb64 = (vb & 31) * 64;
  {
    const int key = t >> 2, dq = t & 3;
    const float* vp = v + (size_t)(kb64 + key) * KLD + kvh * HD + dq * 32;
#pragma unroll
    for (int j = 0; j < 8; ++j) {
      float4 x = *(const float4*)(vp + j * 4);
      const int d = dq * 32 + j * 4;
      TT[d + 0][key] = (__bf16)x.x; TT[d + 1][key] = (__bf16)x.y;
      TT[d + 2][key] = (__bf16)x.z; TT[d + 3][key] = (__bf16)x.w;
    }
  }
  __syncthreads();
  {
    const int dim = t >> 1, kh = (t & 1) * 32;
    __bf16* op = vt + (size_t)kvh * VT_HEAD + (size_t)dim * SEQ + kb64 + kh;
#pragma unroll
    for (int j = 0; j < 8; ++j)
      *(bf16x4*)(op + j * 4) = *(const bf16x4*)&TT[dim][kh + j * 4];
  }
}

// ---- main kernel ----
__global__ __launch_bounds__(256, 2)
void fa_kernel(const float* __restrict__ q, const __bf16* __restrict__ kg,
               const __bf16* __restrict__ vt, float* __restrict__ out) {
  // Per buffer (8KB each): K = 32 keys x 256B (16 chunks of 8 bf16, chunk c
  // at slot c ^ (key&7)); V = 128 dims x 64B (4 chunks of 8 keys, chunk kc at
  // slot kc ^ ((dim>>1)&3)  -> even 4-words/bank for the b64 fragment reads).
  __shared__ __bf16 KB[4][4096];
  __shared__ __bf16 VB[4][4096];

  const int head = blockIdx.x;
  const int ip   = blockIdx.y;          // light 64-row tile = ip, heavy = 31-ip
  const int kvh  = head >> 2;
  const int tid  = threadIdx.x;
  const int wave = tid >> 6;
  const int lane = tid & 63;
  const int l15  = lane & 15;
  const int quad = lane >> 4;
  const int h3   = l15 & 7;

  // per-sub row bases: sub0 = heavy 16 rows, sub1 = light 16 rows
  const int rwS[2] = { (31 - ip) * 64 + wave * 16, ip * 64 + wave * 16 };

  constexpr float QS = 0.08838834764831845f * 1.4426950408889634f; // scale*log2e

  // Q fragments (B-operand of S^T = K*Q^T): B[k=quad*8+j][n=l15]
  bf16x8 qf[2][4];
#pragma unroll
  for (int sub = 0; sub < 2; ++sub) {
    const float* qp = q + (size_t)(rwS[sub] + l15) * QLD + head * HD + quad * 8;
#pragma unroll
    for (int c = 0; c < 4; ++c) {
      float4 a0 = *(const float4*)(qp + c * 32);
      float4 a1 = *(const float4*)(qp + c * 32 + 4);
      bf16x8 f;
      f[0] = (__bf16)(a0.x * QS); f[1] = (__bf16)(a0.y * QS);
      f[2] = (__bf16)(a0.z * QS); f[3] = (__bf16)(a0.w * QS);
      f[4] = (__bf16)(a1.x * QS); f[5] = (__bf16)(a1.y * QS);
      f[6] = (__bf16)(a1.z * QS); f[7] = (__bf16)(a1.w * QS);
      qf[sub][c] = f;
    }
  }

  // DMA lane->global offsets (elements). 2 K-instrs + 2 V-instrs per wave/tile.
  int kgo[2], vgo[2];
#pragma unroll
  for (int j = 0; j < 2; ++j) {
    const int key = (wave * 2 + j) * 4 + (lane >> 4);        // 0..31
    const int c8  = (lane & 15) ^ (key & 7);
    kgo[j] = key * KLD + kvh * HD + c8 * 8;
    const int dim = (wave * 2 + j) * 16 + (lane >> 2);       // 0..127
    const int kc2 = (lane & 3) ^ ((dim >> 1) & 3);           // R9 swizzle fix
    vgo[j] = kvh * VT_HEAD + dim * SEQ + kc2 * 8;
  }

  auto dma_tile = [&](int tt) {
    const int kbase = tt * KVB;     // key offset
    const int buf   = tt & 3;
#pragma unroll
    for (int j = 0; j < 2; ++j)
      __builtin_amdgcn_global_load_lds(
          (const __attribute__((address_space(1))) unsigned int*)(kg + kbase * KLD + kgo[j]),
          (__attribute__((address_space(3))) unsigned int*)&KB[buf][(wave * 2 + j) * 512],
          16, 0, 0);
#pragma unroll
    for (int j = 0; j < 2; ++j)
      __builtin_amdgcn_global_load_lds(
          (const __attribute__((address_space(1))) unsigned int*)(vt + kbase + vgo[j]),
          (__attribute__((address_space(3))) unsigned int*)&VB[buf][(wave * 2 + j) * 512],
          16, 0, 0);
  };

  // fragment byte offsets inside a buffer (bank-uniform by construction)
  int kaddr[4], vaddr[2];
#pragma unroll
  for (int c = 0; c < 4; ++c)
    kaddr[c] = l15 * 256 + (((c * 4 + quad) ^ h3) * 16);
#pragma unroll
  for (int kt = 0; kt < 2; ++kt)
    vaddr[kt] = l15 * 64 + (((kt * 2 + (quad >> 1)) ^ ((l15 >> 1) & 3)) * 16)
              + (quad & 1) * 8;

  f32x4 acc[2][8];
  f32x4 lp[2];
#pragma unroll
  for (int sub = 0; sub < 2; ++sub) {
    lp[sub] = (f32x4){0.f, 0.f, 0.f, 0.f};
#pragma unroll
    for (int nt = 0; nt < 8; ++nt) acc[sub][nt] = (f32x4){0.f, 0.f, 0.f, 0.f};
  }

  const int ntiles = 64 - 2 * ip;   // 32-key tiles; >= 34

  // ---- prologue ----
  dma_tile(0);
  dma_tile(1);
  asm volatile("s_waitcnt vmcnt(4)" ::: "memory");   // tile 0 landed; 1 flying
  __builtin_amdgcn_s_barrier();
  __builtin_amdgcn_sched_barrier(0);

  u32x2 pk[2][2];        // P of tile t-1 (packed bf16, PV B-operand)
  bool  lp_on = false;   // light flag of tile t-1

  for (int t = 0; t < ntiles; ++t) {
    if (t + 2 < ntiles) dma_tile(t + 2);     // depth-2 prefetch

    const bool l_on = (t <= 2 * ip + 1);     // block-uniform
    const char* Kb = (const char*)&KB[t & 3][0];
    const char* Vb = (const char*)&VB[(t - 1) & 3][0];   // prev tile's V

    u32x2 pknew[2][2];
#pragma unroll
    for (int g = 0; g < 2; ++g) {            // key group of 16 within tile
      // ---- QK(t) group g: S^T = K*Q^T, mask, exp2, pack ----
      bf16x8 kf[4];
#pragma unroll
      for (int c = 0; c < 4; ++c)
        kf[c] = *(const bf16x8*)(Kb + kaddr[c] + g * 4096);
#pragma unroll
      for (int sub = 0; sub < 2; ++sub) {
        if (sub == 1 && !l_on) continue;
        f32x4 s = (f32x4){0.f, 0.f, 0.f, 0.f};
        __builtin_amdgcn_s_setprio(1);
#pragma unroll
        for (int c = 0; c < 4; ++c)
          s = __builtin_amdgcn_mfma_f32_16x16x32_bf16(kf[c], qf[sub][c], s, 0, 0, 0);
        __builtin_amdgcn_s_setprio(0);
        if (t * KVB + KVB - 1 > rwS[sub]) {  // causal mask (wave-uniform)
          const int key0  = t * KVB + g * 16 + quad * 4;
          const int myrow = rwS[sub] + l15;
#pragma unroll
          for (int e = 0; e < 4; ++e)
            if (key0 + e > myrow) s[e] = -1e30f;
        }
        f32x4 p;
#pragma unroll
        for (int e = 0; e < 4; ++e) p[e] = __builtin_amdgcn_exp2f(s[e]);
        lp[sub] += p;
        u32x2 pkk;
        pkk.x = pack2(p[0], p[1]);
        pkk.y = pack2(p[2], p[3]);
        pknew[sub][g] = pkk;
      }

      // ---- PV(t-1) group g: independent of this tile's softmax ----
      if (t > 0) {
        bf16x4 vf[8];
#pragma unroll
        for (int nt = 0; nt < 8; ++nt)
          vf[nt] = *(const bf16x4*)(Vb + vaddr[g] + nt * 1024);
        __builtin_amdgcn_s_setprio(1);
#pragma unroll
        for (int nt = 0; nt < 8; ++nt) {
          acc[0][nt] = mfma16(vf[nt], pk[0][g], acc[0][nt]);
          if (lp_on)
            acc[1][nt] = mfma16(vf[nt], pk[1][g], acc[1][nt]);
        }
        __builtin_amdgcn_s_setprio(0);
      }
    }

#pragma unroll
    for (int g = 0; g < 2; ++g) { pk[0][g] = pknew[0][g]; pk[1][g] = pknew[1][g]; }
    lp_on = l_on;

    // ---- counted drain + raw barrier: t+2's batch stays in flight ----
    if (t + 2 < ntiles) {
      asm volatile("s_waitcnt vmcnt(4)" ::: "memory");   // t+1 landed
    } else {
      asm volatile("s_waitcnt vmcnt(0)" ::: "memory");   // tail drain
    }
    __builtin_amdgcn_s_barrier();
    __builtin_amdgcn_sched_barrier(0);
  }

  // ---- drain PV for the last tile ----
  {
    const char* Vb = (const char*)&VB[(ntiles - 1) & 3][0];
#pragma unroll
    for (int g = 0; g < 2; ++g) {
      bf16x4 vf[8];
#pragma unroll
      for (int nt = 0; nt < 8; ++nt)
        vf[nt] = *(const bf16x4*)(Vb + vaddr[g] + nt * 1024);
#pragma unroll
      for (int nt = 0; nt < 8; ++nt) {
        acc[0][nt] = mfma16(vf[nt], pk[0][g], acc[0][nt]);
        if (lp_on)
          acc[1][nt] = mfma16(vf[nt], pk[1][g], acc[1][nt]);
      }
    }
  }

  // ---- epilogue: lane owns row l15 entirely -> scalar inv, float4 stores ----
#pragma unroll
  for (int sub = 0; sub < 2; ++sub) {
    float ls = lp[sub][0] + lp[sub][1] + lp[sub][2] + lp[sub][3];
    ls += __shfl_xor(ls, 16);
    ls += __shfl_xor(ls, 32);
    const float inv = 1.0f / ls;
    float* op = out + (size_t)(rwS[sub] + l15) * QLD + head * HD + quad * 4;
#pragma unroll
    for (int nt = 0; nt < 8; ++nt) {
      f32x4 r = acc[sub][nt];
      float4 w = {r[0] * inv, r[1] * inv, r[2] * inv, r[3] * inv};
      *(float4*)(op + nt * 16) = w;
    }
  }
}

extern "C" void kernel_launch(void* const* d_in, const int* in_sizes, int n_in,
                              void* d_out, int out_size, void* d_ws, size_t ws_size,
                              hipStream_t stream) {
  const float* q = (const float*)d_in[0];
  const float* k = (const float*)d_in[1];
  const float* v = (const float*)d_in[2];
  float* o = (float*)d_out;
  __bf16* kbf = (__bf16*)d_ws;                     // 4 MB: K as bf16
  __bf16* vtb = (__bf16*)d_ws + (size_t)SEQ * KLD; // 4 MB: V^T bf16
  prep_kv<<<2304, 256, 0, stream>>>(k, kbf, v, vtb);
  fa_kernel<<<dim3(32, 16), 256, 0, stream>>>(q, kbf, vtb, o);
}

// Round 5
// 154.402 us; speedup vs baseline: 1.1956x; 1.1531x over previous
//
#include <hip/hip_runtime.h>

// Causal GQA attention: S=2048, H=32, KVH=8, D=128, fp32 in/out.
// R7: work-uniform blocks: wave = 16 heavy rows (sub0) + 16 light rows (sub1);
//     per-block work uniform at 66 sub-iters.
// R8/R9: counted-vmcnt LDS pipelines. Post-mortem fit across R7/R9:
//     iter = C + B with C~2520cyc per 32-key compute, B~1030cyc per barrier
//     rendezvous/drain -- B untouched by any LDS-side restructuring, and C is
//     LDS-pipe-bound (every wave must stream the whole 16KB K+V tile through
//     its registers; 4x amplification is MFMA-structural).
// R10: ZERO-LDS, ZERO-BARRIER. K and V are pre-tiled in ws so every MFMA
// fragment is a perfectly coalesced global_load_dwordx4 straight into
// registers (1KB/instr/wave). No __shared__, no global_load_lds, no
// s_waitcnt asm, no bank conflicts; B -> 0. K double-buffered across tiles
// (reg), V single-buffered covered by QK+softmax. 256-thread blocks kept so
// the 4 waves share L1 (2 blocks x 16KB tile = 32KB = L1); one RAW s_barrier
// per tile (no waitcnt semantics -> no drain) keeps waves L1-aligned.
// Flat grid decoded so kvh == blockIdx.x & 7 == XCD id: each XCD's L2 holds
// only its kv-head's 1MB tile stream (bijective XCD swizzle).

#define SEQ   2048
#define NH    32
#define NKV   8
#define HD    128
#define QLD   4096      // NH*HD
#define KLD   1024      // NKV*HD
#define KVB   32        // keys per tile

typedef __attribute__((ext_vector_type(8))) __bf16 bf16x8;
typedef __attribute__((ext_vector_type(4))) __bf16 bf16x4;
typedef __attribute__((ext_vector_type(2))) __bf16 bf16x2;
typedef __attribute__((ext_vector_type(4))) float  f32x4;
typedef __attribute__((ext_vector_type(4))) short  s16x4;
typedef __attribute__((ext_vector_type(2))) unsigned int u32x2;

static __device__ __forceinline__ unsigned int pack2(float lo, float hi) {
  bf16x2 t; t[0] = (__bf16)lo; t[1] = (__bf16)hi;
  return __builtin_bit_cast(unsigned int, t);
}

// PV matmul: D = A(V^T frag, 2 VGPR) * B(P frag = S^T C-layout regs) + C
static __device__ __forceinline__ f32x4 mfma16(bf16x4 a, u32x2 b, f32x4 c) {
#if __has_builtin(__builtin_amdgcn_mfma_f32_16x16x16bf16_1k)
  return __builtin_amdgcn_mfma_f32_16x16x16bf16_1k(
      __builtin_bit_cast(s16x4, a), __builtin_bit_cast(s16x4, b), c, 0, 0, 0);
#else
  asm volatile("v_mfma_f32_16x16x16_bf16 %0, %1, %2, %0"
               : "+v"(c) : "v"(a), "v"(b));
  return c;
#endif
}

// ---- pre-pass: build fragment-ordered bf16 tiles of K and V^T in ws ----
// KT tile (kvh,t): 8KB, slot = g*256 + c*64 + quad*16 + l15, 8 bf16/slot
//   = K[key = t*32 + g*16 + l15][dim = c*32 + quad*8 .. +8]
//   -> fa's kk[g][c] load at tile + g*2048 + c*512 + lane*8 is 1KB coalesced.
// VT tile (kvh,t): 8KB, slot = nt*64 + quad*16 + l15, 8 bf16/slot
//   = { V[key = t*32 + quad*4 .. +4][dim = nt*16 + l15],        (kt=0 half)
//       V[key = t*32 + 16 + quad*4 .. +4][dim] }                (kt=1 half)
//   -> fa's vv[nt] load at tile + nt*512 + lane*8 is 1KB coalesced and
//      yields BOTH kt-groups' PV A-fragments in one b128.
__global__ void prep_tiles(const float* __restrict__ k, __bf16* __restrict__ kt,
                           const float* __restrict__ v, __bf16* __restrict__ vtt) {
  __shared__ __bf16 TT[HD][34];   // [dim][key32 + pad] (V half only)
  const int bx  = blockIdx.x;
  const int tid = threadIdx.x;
  const int kl  = tid >> 3;       // key-in-tile 0..31
  const int dc  = tid & 7;        // dim chunk of 16: dims dc*16..+16
  if (bx < 512) {                 // ---- K tiles ----
    const int kvh = bx >> 6, t = bx & 63;
    const float* src = k + (size_t)(t * 32 + kl) * KLD + kvh * HD + dc * 16;
    __bf16* dst = kt + (size_t)(kvh * 64 + t) * 4096;
    const int g = kl >> 4, l15 = kl & 15;
#pragma unroll
    for (int h = 0; h < 2; ++h) {
      const int d0 = dc * 16 + h * 8;
      const int c = d0 >> 5, quad = (d0 >> 3) & 3;
      float4 a0 = *(const float4*)(src + h * 8);
      float4 a1 = *(const float4*)(src + h * 8 + 4);
      bf16x8 f;
      f[0] = (__bf16)a0.x; f[1] = (__bf16)a0.y; f[2] = (__bf16)a0.z; f[3] = (__bf16)a0.w;
      f[4] = (__bf16)a1.x; f[5] = (__bf16)a1.y; f[6] = (__bf16)a1.z; f[7] = (__bf16)a1.w;
      const int slot = g * 256 + c * 64 + quad * 16 + l15;
      *(bf16x8*)(dst + slot * 8) = f;
    }
  } else {                        // ---- V tiles (transpose via LDS) ----
    const int b = bx - 512, kvh = b >> 6, t = b & 63;
    const float* src = v + (size_t)(t * 32 + kl) * KLD + kvh * HD + dc * 16;
#pragma unroll
    for (int jj = 0; jj < 4; ++jj) {
      float4 x = *(const float4*)(src + jj * 4);
      const int d = dc * 16 + jj * 4;
      TT[d + 0][kl] = (__bf16)x.x; TT[d + 1][kl] = (__bf16)x.y;
      TT[d + 2][kl] = (__bf16)x.z; TT[d + 3][kl] = (__bf16)x.w;
    }
    __syncthreads();
    __bf16* dst = vtt + (size_t)(kvh * 64 + t) * 4096;
#pragma unroll
    for (int ss = 0; ss < 2; ++ss) {
      const int s   = tid + ss * 256;
      const int nt  = s >> 6, quad = (s >> 4) & 3, l15 = s & 15;
      const int dim = nt * 16 + l15;
      bf16x8 f;
#pragma unroll
      for (int e = 0; e < 4; ++e) {
        f[e]     = TT[dim][quad * 4 + e];
        f[4 + e] = TT[dim][16 + quad * 4 + e];
      }
      *(bf16x8*)(dst + s * 8) = f;
    }
  }
}

// ---- main kernel: zero LDS, zero memory-barriers ----
__global__ __launch_bounds__(256, 2)
void fa_kernel(const float* __restrict__ q, const __bf16* __restrict__ kt,
               const __bf16* __restrict__ vtt, float* __restrict__ out) {
  // Flat-grid decode: kvh = bid&7 (== XCD on round-robin dispatch),
  // head = kvh*4 + (slot&3), ip = slot>>2. Bijective over 512 blocks.
  const int bid  = blockIdx.x;
  const int kvh  = bid & 7;
  const int slot = bid >> 3;
  const int head = kvh * 4 + (slot & 3);
  const int ip   = slot >> 2;           // light 64-row tile = ip, heavy = 31-ip
  const int tid  = threadIdx.x;
  const int wave = tid >> 6;
  const int lane = tid & 63;
  const int l15  = lane & 15;
  const int quad = lane >> 4;

  // per-sub row bases: sub0 = heavy 16 rows, sub1 = light 16 rows
  const int rwS[2] = { (31 - ip) * 64 + wave * 16, ip * 64 + wave * 16 };

  constexpr float QS = 0.08838834764831845f * 1.4426950408889634f; // scale*log2e

  // Q fragments (B-operand of S^T = K*Q^T): B[k=quad*8+j][n=l15]
  bf16x8 qf[2][4];
#pragma unroll
  for (int sub = 0; sub < 2; ++sub) {
    const float* qp = q + (size_t)(rwS[sub] + l15) * QLD + head * HD + quad * 8;
#pragma unroll
    for (int c = 0; c < 4; ++c) {
      float4 a0 = *(const float4*)(qp + c * 32);
      float4 a1 = *(const float4*)(qp + c * 32 + 4);
      bf16x8 f;
      f[0] = (__bf16)(a0.x * QS); f[1] = (__bf16)(a0.y * QS);
      f[2] = (__bf16)(a0.z * QS); f[3] = (__bf16)(a0.w * QS);
      f[4] = (__bf16)(a1.x * QS); f[5] = (__bf16)(a1.y * QS);
      f[6] = (__bf16)(a1.z * QS); f[7] = (__bf16)(a1.w * QS);
      qf[sub][c] = f;
    }
  }

  const __bf16* KT0 = kt  + (size_t)(kvh * 64) * 4096;
  const __bf16* VT0 = vtt + (size_t)(kvh * 64) * 4096;
  const int loff = lane * 8;   // elems

  f32x4 acc[2][8];
  f32x4 lp[2];
#pragma unroll
  for (int sub = 0; sub < 2; ++sub) {
    lp[sub] = (f32x4){0.f, 0.f, 0.f, 0.f};
#pragma unroll
    for (int nt = 0; nt < 8; ++nt) acc[sub][nt] = (f32x4){0.f, 0.f, 0.f, 0.f};
  }

  const int ntiles = 64 - 2 * ip;   // even, >= 34

  bf16x8 kk0[2][4], kk1[2][4];
  // prologue: K(0) -> kk0
#pragma unroll
  for (int g = 0; g < 2; ++g)
#pragma unroll
    for (int c = 0; c < 4; ++c)
      kk0[g][c] = *(const bf16x8*)(KT0 + g * 2048 + c * 512 + loff);

  auto body = [&](int t, bf16x8 (&kc)[2][4], bf16x8 (&kn)[2][4]) {
    // V(t) loads first (consumed this body, covered by QK+softmax) ...
    bf16x8 vv[8];
    const __bf16* vtile = VT0 + (size_t)t * 4096;
#pragma unroll
    for (int nt = 0; nt < 8; ++nt)
      vv[nt] = *(const bf16x8*)(vtile + nt * 512 + loff);
    // ... then K(t+1) prefetch (consumed next body)
    if (t + 1 < ntiles) {
      const __bf16* ktile = KT0 + (size_t)(t + 1) * 4096;
#pragma unroll
      for (int g = 0; g < 2; ++g)
#pragma unroll
        for (int c = 0; c < 4; ++c)
          kn[g][c] = *(const bf16x8*)(ktile + g * 2048 + c * 512 + loff);
    }

    const bool l_on = (t <= 2 * ip + 1);   // block-uniform

    // ---- S^T = K*Q^T (C-layout: key = quad*4+e, row = l15), then exp2 ----
    u32x2 pknew[2][2];
#pragma unroll
    for (int g = 0; g < 2; ++g) {
#pragma unroll
      for (int sub = 0; sub < 2; ++sub) {
        if (sub == 1 && !l_on) continue;
        f32x4 s = (f32x4){0.f, 0.f, 0.f, 0.f};
        __builtin_amdgcn_s_setprio(1);
#pragma unroll
        for (int c = 0; c < 4; ++c)
          s = __builtin_amdgcn_mfma_f32_16x16x32_bf16(kc[g][c], qf[sub][c], s, 0, 0, 0);
        __builtin_amdgcn_s_setprio(0);
        if (t * KVB + KVB - 1 > rwS[sub]) {  // causal mask (wave-uniform)
          const int key0  = t * KVB + g * 16 + quad * 4;
          const int myrow = rwS[sub] + l15;
#pragma unroll
          for (int e = 0; e < 4; ++e)
            if (key0 + e > myrow) s[e] = -1e30f;
        }
        f32x4 p;
#pragma unroll
        for (int e = 0; e < 4; ++e) p[e] = __builtin_amdgcn_exp2f(s[e]);
        lp[sub] += p;
        u32x2 pkk;
        pkk.x = pack2(p[0], p[1]);
        pkk.y = pack2(p[2], p[3]);
        pknew[sub][g] = pkk;
      }
    }

    // ---- O^T += V^T * P  (vv[nt] lo-half = kt0 frag, hi-half = kt1) ----
#pragma unroll
    for (int kt2 = 0; kt2 < 2; ++kt2) {
      __builtin_amdgcn_s_setprio(1);
#pragma unroll
      for (int nt = 0; nt < 8; ++nt) {
        bf16x4 vf;
#pragma unroll
        for (int e = 0; e < 4; ++e) vf[e] = vv[nt][kt2 * 4 + e];
        acc[0][nt] = mfma16(vf, pknew[0][kt2], acc[0][nt]);
        if (l_on)
          acc[1][nt] = mfma16(vf, pknew[1][kt2], acc[1][nt]);
      }
      __builtin_amdgcn_s_setprio(0);
    }

    // raw rendezvous only (no waitcnt semantics): keeps the 4 waves
    // time-aligned so they share L1 lines on the same tile stream.
    __builtin_amdgcn_s_barrier();
  };

  for (int t = 0; t < ntiles; t += 2) {
    body(t,     kk0, kk1);
    body(t + 1, kk1, kk0);
  }

  // ---- epilogue: lane owns row l15 entirely -> scalar inv, float4 stores ----
#pragma unroll
  for (int sub = 0; sub < 2; ++sub) {
    float ls = lp[sub][0] + lp[sub][1] + lp[sub][2] + lp[sub][3];
    ls += __shfl_xor(ls, 16);
    ls += __shfl_xor(ls, 32);
    const float inv = 1.0f / ls;
    float* op = out + (size_t)(rwS[sub] + l15) * QLD + head * HD + quad * 4;
#pragma unroll
    for (int nt = 0; nt < 8; ++nt) {
      f32x4 r = acc[sub][nt];
      float4 w = {r[0] * inv, r[1] * inv, r[2] * inv, r[3] * inv};
      *(float4*)(op + nt * 16) = w;
    }
  }
}

extern "C" void kernel_launch(void* const* d_in, const int* in_sizes, int n_in,
                              void* d_out, int out_size, void* d_ws, size_t ws_size,
                              hipStream_t stream) {
  const float* q = (const float*)d_in[0];
  const float* k = (const float*)d_in[1];
  const float* v = (const float*)d_in[2];
  float* o = (float*)d_out;
  __bf16* ktb = (__bf16*)d_ws;                          // 4 MB: K tiles
  __bf16* vtb = (__bf16*)d_ws + (size_t)SEQ * KLD;      // 4 MB: V^T tiles
  prep_tiles<<<1024, 256, 0, stream>>>(k, ktb, v, vtb);
  fa_kernel<<<512, 256, 0, stream>>>(q, ktb, vtb, o);
}